// Round 10
// baseline (139.633 us; speedup 1.0000x reference)
//
#include <hip/hip_runtime.h>
#include <cmath>

// PillarFeatureNet fused: augment(10ch) -> linear(64) -> BN(inference) -> exact GELU -> max over points.
// Key algebra: y[m][o] = f0*A0 + f1*A1 + f2*A2 + f3*A3 + C_pillar  (C-deferred: scan dot only).
// GELU valley-shaped => max_m gelu(y_m) = max(gelu(max y), gelu(min y)): 2 gelus per (n,o).
// Masked points contribute y = b (BN of 0), merged once when num_points < 32.
// points_mean sums ALL 32 raw rows (reference semantics); mask applies only to the matmul.
//
// R10 (R9 post-mortem: exact-n scan = null; R4 fast-gelu = small -> VALU COUNT is not the
//      limiter; remaining suspect is the DS pipe (shared across 4 SIMDs/CU) + per-read
//      dependent LDS latency in the scan chain):
//   - LDS ELIMINATED. The LDS round-trip was only a lane transpose; v_readlane does the
//     same broadcast in-register: point m's float4 lives in lane m (pillar A) / m+32
//     (pillar B) of this wave's own f0/f1 registers. Full 8-point blocks use immediate
//     lane indices; the partial block uses uniform SGPR indices (n via readfirstlane).
//     Each FMA consumes the readlane result as its single SGPR operand (ISA-legal).
//     +4 readlanes/pt (+~132 VALU/pair) for zero DS ops / staging / fence / latency.
//   - everything else == R9/R6 chassis: one-shot dual-pair waves, 2-pairs-per-wave grid,
//     DPP mean reduction, C-deferral, rcp means, packed branchless gelu.

typedef float f32x2 __attribute__((ext_vector_type(2)));

__device__ __forceinline__ float max3f(float a, float b, float c) {
    float d;
    asm("v_max3_f32 %0, %1, %2, %3" : "=v"(d) : "v"(a), "v"(b), "v"(c));
    return d;
}
__device__ __forceinline__ float min3f(float a, float b, float c) {
    float d;
    asm("v_min3_f32 %0, %1, %2, %3" : "=v"(d) : "v"(a), "v"(b), "v"(c));
    return d;
}
__device__ __forceinline__ f32x2 pk_fma(f32x2 a, f32x2 b, f32x2 c) {
    f32x2 d;
    asm("v_pk_fma_f32 %0, %1, %2, %3" : "=v"(d) : "v"(a), "v"(b), "v"(c));
    return d;
}
__device__ __forceinline__ f32x2 pk_mul(f32x2 a, f32x2 b) {
    f32x2 d;
    asm("v_pk_mul_f32 %0, %1, %2" : "=v"(d) : "v"(a), "v"(b));
    return d;
}
__device__ __forceinline__ float fast_exp2(float a) {
    float d;
    asm("v_exp_f32 %0, %1" : "=v"(d) : "v"(a));
    return d;
}
__device__ __forceinline__ float rlane(float v, int l) {
    return __builtin_bit_cast(float, __builtin_amdgcn_readlane(__builtin_bit_cast(int, v), l));
}

// Packed exact-GELU for 2 values (A&S 7.1.26 erf, branchless). |err| ~2e-6 abs.
__device__ __forceinline__ f32x2 gelu2(f32x2 x) {
    const f32x2 c_t    = {0.70710678f, 0.70710678f};
    const f32x2 c_p    = {0.3275911f, 0.3275911f};
    const f32x2 c_one  = {1.0f, 1.0f};
    const f32x2 b1 = {-0.254829592f, -0.254829592f};
    const f32x2 b2 = { 0.284496736f,  0.284496736f};
    const f32x2 b3 = {-1.421413741f, -1.421413741f};
    const f32x2 b4 = { 1.453152027f,  1.453152027f};
    const f32x2 b5 = {-1.061405429f, -1.061405429f};
    const f32x2 c_k = {-1.02013963f, -1.02013963f};   // arg = -t^2*log2(e)

    f32x2 ax = {fabsf(x.x), fabsf(x.y)};
    f32x2 t  = pk_mul(ax, c_t);
    f32x2 u  = pk_fma(t, c_p, c_one);
    f32x2 s  = {__builtin_amdgcn_rcpf(u.x), __builtin_amdgcn_rcpf(u.y)};
    f32x2 poly = pk_fma(b5, s, b4);
    poly = pk_fma(poly, s, b3);
    poly = pk_fma(poly, s, b2);
    poly = pk_fma(poly, s, b1);
    poly = pk_mul(poly, s);
    f32x2 t3  = pk_mul(ax, c_k);
    f32x2 arg = pk_mul(t, t3);
    f32x2 e   = {fast_exp2(arg.x), fast_exp2(arg.y)};
    f32x2 E   = pk_fma(poly, e, c_one);
    f32x2 h   = pk_mul(x, (f32x2){0.5f, 0.5f});
    f32x2 hax = pk_mul(ax, (f32x2){0.5f, 0.5f});
    return pk_fma(hax, E, h);
}

// DPP half-wave sums: returns sum(lanes 0..31) and sum(lanes 32..63). Pure VALU.
template <int CTRL, int ROW_MASK>
__device__ __forceinline__ float dpp_add(float v) {
    int x = __builtin_amdgcn_update_dpp(0, __builtin_bit_cast(int, v), CTRL, ROW_MASK, 0xf, false);
    return v + __builtin_bit_cast(float, x);
}
__device__ __forceinline__ void half_sums(float v, float& sA, float& sB) {
    v = dpp_add<0x111, 0xf>(v);   // row_shr:1
    v = dpp_add<0x112, 0xf>(v);   // row_shr:2
    v = dpp_add<0x114, 0xf>(v);   // row_shr:4
    v = dpp_add<0x118, 0xf>(v);   // row_shr:8  -> lane15/31/47/63 hold 16-lane sums
    v = dpp_add<0x142, 0xa>(v);   // row_bcast:15 into rows 1,3 -> lane31/63 hold 32-lane sums
    sA = __builtin_bit_cast(float, __builtin_amdgcn_readlane(__builtin_bit_cast(int, v), 31));
    sB = __builtin_bit_cast(float, __builtin_amdgcn_readlane(__builtin_bit_cast(int, v), 63));
}

// 8-point straight-line block, data from the wave's own registers via readlane with
// IMMEDIATE lane indices. Dual minmax accumulator chains.
template <int OFF>
__device__ __forceinline__ void scan8_rl(const float4& f,
                                         float A0, float A1, float A2, float A3,
                                         float& mx0, float& mn0, float& mx1, float& mn1) {
    float y[8];
    #pragma unroll
    for (int j = 0; j < 8; ++j) {
        const float px = rlane(f.x, OFF + j);
        const float py = rlane(f.y, OFF + j);
        const float pz = rlane(f.z, OFF + j);
        const float pw = rlane(f.w, OFF + j);
        y[j] = fmaf(px, A0, fmaf(py, A1, fmaf(pz, A2, pw * A3)));
    }
    mx0 = max3f(mx0, y[0], y[1]); mn0 = min3f(mn0, y[0], y[1]);
    mx1 = max3f(mx1, y[2], y[3]); mn1 = min3f(mn1, y[2], y[3]);
    mx0 = max3f(mx0, y[4], y[5]); mn0 = min3f(mn0, y[4], y[5]);
    mx1 = max3f(mx1, y[6], y[7]); mn1 = min3f(mn1, y[6], y[7]);
}

// Exact-n scan from registers: full 8-blocks via uniform branches + guarded partial block
// with uniform SGPR lane indices (n is readfirstlane'd -> provably wave-uniform).
template <int LOFF>   // 0 = pillar A (lanes 0..31), 32 = pillar B (lanes 32..63)
__device__ __forceinline__ void scan_pillar_rl(const float4& f, int n,
                                               float A0, float A1, float A2, float A3,
                                               float& dmax, float& dmin) {
    float mx0 = -INFINITY, mn0 = INFINITY, mx1 = -INFINITY, mn1 = INFINITY;
    const int nfull = n >> 3;
    if (nfull > 0) scan8_rl<LOFF +  0>(f, A0, A1, A2, A3, mx0, mn0, mx1, mn1);
    if (nfull > 1) scan8_rl<LOFF +  8>(f, A0, A1, A2, A3, mx0, mn0, mx1, mn1);
    if (nfull > 2) scan8_rl<LOFF + 16>(f, A0, A1, A2, A3, mx0, mn0, mx1, mn1);
    if (nfull > 3) scan8_rl<LOFF + 24>(f, A0, A1, A2, A3, mx0, mn0, mx1, mn1);
    const int rem = n & 7;
    if (rem) {
        const int base = LOFF + (nfull << 3);
        #pragma unroll
        for (int j = 0; j < 7; ++j) {
            if (j < rem) {   // rem uniform -> scalar branch
                const float px = rlane(f.x, base + j);
                const float py = rlane(f.y, base + j);
                const float pz = rlane(f.z, base + j);
                const float pw = rlane(f.w, base + j);
                const float y = fmaf(px, A0, fmaf(py, A1, fmaf(pz, A2, pw * A3)));
                mx0 = fmaxf(mx0, y);
                mn0 = fminf(mn0, y);
            }
        }
    }
    dmax = fmaxf(mx0, mx1);
    dmin = fminf(mn0, mn1);
}

__global__ __launch_bounds__(256) void pfn_kernel(
    const float* __restrict__ features,   // (N, 32, 4)
    const int*   __restrict__ num_points, // (N,)
    const int*   __restrict__ coors,      // (N, 4)
    const float* __restrict__ W,          // (64, 10)
    const float* __restrict__ gamma,      // (64,)
    const float* __restrict__ beta,       // (64,)
    const float* __restrict__ rmean,      // (64,)
    const float* __restrict__ rvar,       // (64,)
    float*       __restrict__ out,        // (N, 64)
    int nTotal)
{
    const int lane = threadIdx.x & 63;
    const int wid  = threadIdx.x >> 6;
    const int wv   = blockIdx.x * 4 + wid;
    const int nPairs = (nTotal + 1) >> 1;
    const int p0 = wv * 2;
    if (p0 >= nPairs) return;
    const int p1 = (p0 + 1 < nPairs) ? (p0 + 1) : p0;   // clamp: duplicate work, benign

    // ---- issue both 1KB feature loads up front ----
    const float4* fbase = reinterpret_cast<const float4*>(features);
    const float4 f0 = fbase[(size_t)p0 * 64 + lane];    // lane l -> pillar (2p+(l>=32)), point (l&31)
    const float4 f1 = fbase[(size_t)p1 * 64 + lane];

    const int i0A = 2 * p0;
    const bool h0B = (2 * p0 + 1 < nTotal);
    const int i0B = h0B ? (2 * p0 + 1) : (nTotal - 1);
    const int i1A = 2 * p1;
    const bool h1B = (2 * p1 + 1 < nTotal);
    const int i1B = h1B ? (2 * p1 + 1) : (nTotal - 1);

    // n's readfirstlane'd: provably uniform -> scalar branches + legal SGPR readlane idx
    const int n0A = __builtin_amdgcn_readfirstlane(num_points[i0A]);
    const int n0B = __builtin_amdgcn_readfirstlane(num_points[i0B]);
    const int n1A = __builtin_amdgcn_readfirstlane(num_points[i1A]);
    const int n1B = __builtin_amdgcn_readfirstlane(num_points[i1B]);
    const int4 c0A = reinterpret_cast<const int4*>(coors)[i0A];
    const int4 c0B = reinterpret_cast<const int4*>(coors)[i0B];
    const int4 c1A = reinterpret_cast<const int4*>(coors)[i1A];
    const int4 c1B = reinterpret_cast<const int4*>(coors)[i1B];

    // lane == output channel o
    const int o = lane;
    const float w0 = W[o*10+0], w1 = W[o*10+1], w2 = W[o*10+2], w3 = W[o*10+3],
                w4 = W[o*10+4], w5 = W[o*10+5], w6 = W[o*10+6], w7 = W[o*10+7],
                w8 = W[o*10+8], w9 = W[o*10+9];
    const float a = gamma[o] / sqrtf(rvar[o] + 1e-3f);
    const float b = fmaf(-rmean[o], a, beta[o]);
    const float A0 = a*(w0+w4+w7), A1 = a*(w1+w5+w8), A2 = a*(w2+w6+w9), A3 = a*w3;

    // ---- DPP half-wave sums (off critical path thanks to C-deferral) ----
    float s0Ax, s0Bx, s0Ay, s0By, s0Az, s0Bz;
    float s1Ax, s1Bx, s1Ay, s1By, s1Az, s1Bz;
    half_sums(f0.x, s0Ax, s0Bx);
    half_sums(f0.y, s0Ay, s0By);
    half_sums(f0.z, s0Az, s0Bz);
    half_sums(f1.x, s1Ax, s1Bx);
    half_sums(f1.y, s1Ay, s1By);
    half_sums(f1.z, s1Az, s1Bz);

    // means via v_rcp (<=1ulp), voxel-center offsets, K, C  (x4 pillars)
    const float rc0A = __builtin_amdgcn_rcpf((float)n0A);
    const float rc0B = __builtin_amdgcn_rcpf((float)n0B);
    const float rc1A = __builtin_amdgcn_rcpf((float)n1A);
    const float rc1B = __builtin_amdgcn_rcpf((float)n1B);

    const float K0A = -((s0Ax*rc0A)*w4 + (s0Ay*rc0A)*w5 + (s0Az*rc0A)*w6
                      + fmaf((float)c0A.z, 0.2f, 0.1f)*w7
                      + fmaf((float)c0A.y, 0.2f, -39.9f)*w8
                      + fmaf((float)c0A.x, 4.0f, -1.0f)*w9);
    const float K0B = -((s0Bx*rc0B)*w4 + (s0By*rc0B)*w5 + (s0Bz*rc0B)*w6
                      + fmaf((float)c0B.z, 0.2f, 0.1f)*w7
                      + fmaf((float)c0B.y, 0.2f, -39.9f)*w8
                      + fmaf((float)c0B.x, 4.0f, -1.0f)*w9);
    const float K1A = -((s1Ax*rc1A)*w4 + (s1Ay*rc1A)*w5 + (s1Az*rc1A)*w6
                      + fmaf((float)c1A.z, 0.2f, 0.1f)*w7
                      + fmaf((float)c1A.y, 0.2f, -39.9f)*w8
                      + fmaf((float)c1A.x, 4.0f, -1.0f)*w9);
    const float K1B = -((s1Bx*rc1B)*w4 + (s1By*rc1B)*w5 + (s1Bz*rc1B)*w6
                      + fmaf((float)c1B.z, 0.2f, 0.1f)*w7
                      + fmaf((float)c1B.y, 0.2f, -39.9f)*w8
                      + fmaf((float)c1B.x, 4.0f, -1.0f)*w9);
    const float C0A = fmaf(a, K0A, b), C0B = fmaf(a, K0B, b);
    const float C1A = fmaf(a, K1A, b), C1B = fmaf(a, K1B, b);

    // ---- exact-n in-register scans (C-deferred, zero DS traffic) ----
    float d0Amax, d0Amin, d0Bmax, d0Bmin, d1Amax, d1Amin, d1Bmax, d1Bmin;
    scan_pillar_rl<0> (f0, n0A, A0, A1, A2, A3, d0Amax, d0Amin);
    scan_pillar_rl<32>(f0, n0B, A0, A1, A2, A3, d0Bmax, d0Bmin);
    scan_pillar_rl<0> (f1, n1A, A0, A1, A2, A3, d1Amax, d1Amin);
    scan_pillar_rl<32>(f1, n1B, A0, A1, A2, A3, d1Bmax, d1Bmin);

    float vmax0A = d0Amax + C0A, vmin0A = d0Amin + C0A;
    float vmax0B = d0Bmax + C0B, vmin0B = d0Bmin + C0B;
    float vmax1A = d1Amax + C1A, vmin1A = d1Amin + C1A;
    float vmax1B = d1Bmax + C1B, vmin1B = d1Bmin + C1B;

    if (n0A < 32) { vmax0A = fmaxf(vmax0A, b); vmin0A = fminf(vmin0A, b); }
    if (n0B < 32) { vmax0B = fmaxf(vmax0B, b); vmin0B = fminf(vmin0B, b); }
    if (n1A < 32) { vmax1A = fmaxf(vmax1A, b); vmin1A = fminf(vmin1A, b); }
    if (n1B < 32) { vmax1B = fmaxf(vmax1B, b); vmin1B = fminf(vmin1B, b); }

    // valley property + packed branchless gelu (4 independent evals: good ILP)
    const f32x2 g0A = gelu2((f32x2){vmax0A, vmin0A});
    const f32x2 g0B = gelu2((f32x2){vmax0B, vmin0B});
    const f32x2 g1A = gelu2((f32x2){vmax1A, vmin1A});
    const f32x2 g1B = gelu2((f32x2){vmax1B, vmin1B});

    out[(size_t)i0A * 64 + o] = fmaxf(g0A.x, g0A.y);
    if (h0B) out[(size_t)i0B * 64 + o] = fmaxf(g0B.x, g0B.y);
    out[(size_t)i1A * 64 + o] = fmaxf(g1A.x, g1A.y);
    if (h1B) out[(size_t)i1B * 64 + o] = fmaxf(g1B.x, g1B.y);
}

extern "C" void kernel_launch(void* const* d_in, const int* in_sizes, int n_in,
                              void* d_out, int out_size, void* d_ws, size_t ws_size,
                              hipStream_t stream) {
    const float* features   = (const float*)d_in[0];
    const int*   num_points = (const int*)  d_in[1];
    const int*   coors      = (const int*)  d_in[2];
    const float* W          = (const float*)d_in[3];
    const float* gamma      = (const float*)d_in[4];
    const float* beta       = (const float*)d_in[5];
    const float* rmean      = (const float*)d_in[6];
    const float* rvar       = (const float*)d_in[7];
    float* out = (float*)d_out;

    const int nTotal = in_sizes[1];  // N pillars

    // 4 waves x 2 consecutive pairs per wave = 8 pairs/block (R6-verified grid)
    const int nPairs = (nTotal + 1) / 2;
    int blocks = (nPairs + 7) / 8;
    if (blocks < 1) blocks = 1;
    pfn_kernel<<<blocks, 256, 0, stream>>>(features, num_points, coors, W,
                                           gamma, beta, rmean, rvar, out, nTotal);
}

// Round 11
// 127.252 us; speedup vs baseline: 1.0973x; 1.0973x over previous
//
#include <hip/hip_runtime.h>
#include <cmath>

// PillarFeatureNet fused: augment(10ch) -> linear(64) -> BN(inference) -> exact GELU -> max over points.
// Key algebra: y[m][o] = f0*A0 + f1*A1 + f2*A2 + f3*A3 + C_pillar  (C-deferred: scan dot only).
// GELU valley-shaped => max_m gelu(y_m) = max(gelu(max y), gelu(min y)): 2 gelus per (n,o).
// Masked points contribute y = b (BN of 0), merged once when num_points < 32.
// points_mean sums ALL 32 raw rows (reference semantics); mask applies only to the matmul.
//
// R11 (R10 post-mortem: readlane scan ADDED VALU busy-time -> DS pipe wasn't the limiter;
//      revert to R9 chassis. Across R2-R10: essential VALU ~11us vs 40us wall, VALU-count
//      cuts all null -> remaining suspect is PER-WAVE serialization: 25k one-shot waves x
//      (constant setup + lockstep load stall) + 6250-block ramp/drain):
//   - 4 PAIRS PER WAVE, ONE-SHOT, NO ROTATION (R8's failure was the prefetch rotation's
//     VGPR doubling, not work-per-wave): 12500 waves exactly (N=100k), constant setup
//     amortized 2x, all 20 VMEM loads issued in one up-front burst -> one stall covers
//     4 pairs of compute, 4 independent scan streams of ILP.
//   - all per-pair state in flat unrolled arrays (compile-time indices, no scratch).
//   - scan/DPP/C-deferral/gelu identical to R9 (verified ~39.6us).

typedef float f32x2 __attribute__((ext_vector_type(2)));

__device__ __forceinline__ float max3f(float a, float b, float c) {
    float d;
    asm("v_max3_f32 %0, %1, %2, %3" : "=v"(d) : "v"(a), "v"(b), "v"(c));
    return d;
}
__device__ __forceinline__ float min3f(float a, float b, float c) {
    float d;
    asm("v_min3_f32 %0, %1, %2, %3" : "=v"(d) : "v"(a), "v"(b), "v"(c));
    return d;
}
__device__ __forceinline__ f32x2 pk_fma(f32x2 a, f32x2 b, f32x2 c) {
    f32x2 d;
    asm("v_pk_fma_f32 %0, %1, %2, %3" : "=v"(d) : "v"(a), "v"(b), "v"(c));
    return d;
}
__device__ __forceinline__ f32x2 pk_mul(f32x2 a, f32x2 b) {
    f32x2 d;
    asm("v_pk_mul_f32 %0, %1, %2" : "=v"(d) : "v"(a), "v"(b));
    return d;
}
__device__ __forceinline__ float fast_exp2(float a) {
    float d;
    asm("v_exp_f32 %0, %1" : "=v"(d) : "v"(a));
    return d;
}

// Packed exact-GELU for 2 values (A&S 7.1.26 erf, branchless). |err| ~2e-6 abs.
__device__ __forceinline__ f32x2 gelu2(f32x2 x) {
    const f32x2 c_t    = {0.70710678f, 0.70710678f};
    const f32x2 c_p    = {0.3275911f, 0.3275911f};
    const f32x2 c_one  = {1.0f, 1.0f};
    const f32x2 b1 = {-0.254829592f, -0.254829592f};
    const f32x2 b2 = { 0.284496736f,  0.284496736f};
    const f32x2 b3 = {-1.421413741f, -1.421413741f};
    const f32x2 b4 = { 1.453152027f,  1.453152027f};
    const f32x2 b5 = {-1.061405429f, -1.061405429f};
    const f32x2 c_k = {-1.02013963f, -1.02013963f};   // arg = -t^2*log2(e)

    f32x2 ax = {fabsf(x.x), fabsf(x.y)};
    f32x2 t  = pk_mul(ax, c_t);
    f32x2 u  = pk_fma(t, c_p, c_one);
    f32x2 s  = {__builtin_amdgcn_rcpf(u.x), __builtin_amdgcn_rcpf(u.y)};
    f32x2 poly = pk_fma(b5, s, b4);
    poly = pk_fma(poly, s, b3);
    poly = pk_fma(poly, s, b2);
    poly = pk_fma(poly, s, b1);
    poly = pk_mul(poly, s);
    f32x2 t3  = pk_mul(ax, c_k);
    f32x2 arg = pk_mul(t, t3);
    f32x2 e   = {fast_exp2(arg.x), fast_exp2(arg.y)};
    f32x2 E   = pk_fma(poly, e, c_one);
    f32x2 h   = pk_mul(x, (f32x2){0.5f, 0.5f});
    f32x2 hax = pk_mul(ax, (f32x2){0.5f, 0.5f});
    return pk_fma(hax, E, h);
}

// DPP half-wave sums: returns sum(lanes 0..31) and sum(lanes 32..63). Pure VALU.
template <int CTRL, int ROW_MASK>
__device__ __forceinline__ float dpp_add(float v) {
    int x = __builtin_amdgcn_update_dpp(0, __builtin_bit_cast(int, v), CTRL, ROW_MASK, 0xf, false);
    return v + __builtin_bit_cast(float, x);
}
__device__ __forceinline__ void half_sums(float v, float& sA, float& sB) {
    v = dpp_add<0x111, 0xf>(v);   // row_shr:1
    v = dpp_add<0x112, 0xf>(v);   // row_shr:2
    v = dpp_add<0x114, 0xf>(v);   // row_shr:4
    v = dpp_add<0x118, 0xf>(v);   // row_shr:8  -> lane15/31/47/63 hold 16-lane sums
    v = dpp_add<0x142, 0xa>(v);   // row_bcast:15 into rows 1,3 -> lane31/63 hold 32-lane sums
    sA = __builtin_bit_cast(float, __builtin_amdgcn_readlane(__builtin_bit_cast(int, v), 31));
    sB = __builtin_bit_cast(float, __builtin_amdgcn_readlane(__builtin_bit_cast(int, v), 63));
}

// 8-point straight-line block: immediate-offset broadcast ds_reads, dual minmax chains.
__device__ __forceinline__ void scan8(const float4* b4,
                                      float A0, float A1, float A2, float A3,
                                      float& mx0, float& mn0, float& mx1, float& mn1) {
    float4 t0 = b4[0], t1 = b4[1], t2 = b4[2], t3 = b4[3];
    float4 t4 = b4[4], t5 = b4[5], t6 = b4[6], t7 = b4[7];
    float y0 = fmaf(t0.x, A0, fmaf(t0.y, A1, fmaf(t0.z, A2, t0.w * A3)));
    float y1 = fmaf(t1.x, A0, fmaf(t1.y, A1, fmaf(t1.z, A2, t1.w * A3)));
    float y2 = fmaf(t2.x, A0, fmaf(t2.y, A1, fmaf(t2.z, A2, t2.w * A3)));
    float y3 = fmaf(t3.x, A0, fmaf(t3.y, A1, fmaf(t3.z, A2, t3.w * A3)));
    float y4 = fmaf(t4.x, A0, fmaf(t4.y, A1, fmaf(t4.z, A2, t4.w * A3)));
    float y5 = fmaf(t5.x, A0, fmaf(t5.y, A1, fmaf(t5.z, A2, t5.w * A3)));
    float y6 = fmaf(t6.x, A0, fmaf(t6.y, A1, fmaf(t6.z, A2, t6.w * A3)));
    float y7 = fmaf(t7.x, A0, fmaf(t7.y, A1, fmaf(t7.z, A2, t7.w * A3)));
    mx0 = max3f(mx0, y0, y1); mn0 = min3f(mn0, y0, y1);
    mx1 = max3f(mx1, y2, y3); mn1 = min3f(mn1, y2, y3);
    mx0 = max3f(mx0, y4, y5); mn0 = min3f(mn0, y4, y5);
    mx1 = max3f(mx1, y6, y7); mn1 = min3f(mn1, y6, y7);
}

// Exact-n scan: full 8-blocks via uniform branches + guarded partial block (reads only
// valid points; n is wave-uniform so all guards are coherent branches, no divergence).
__device__ __forceinline__ void scan_pillar(const float4* base, int n,
                                            float A0, float A1, float A2, float A3,
                                            float& dmax, float& dmin) {
    float mx0 = -INFINITY, mn0 = INFINITY, mx1 = -INFINITY, mn1 = INFINITY;
    const int nfull = n >> 3;
    if (nfull > 0) scan8(base,      A0, A1, A2, A3, mx0, mn0, mx1, mn1);
    if (nfull > 1) scan8(base + 8,  A0, A1, A2, A3, mx0, mn0, mx1, mn1);
    if (nfull > 2) scan8(base + 16, A0, A1, A2, A3, mx0, mn0, mx1, mn1);
    if (nfull > 3) scan8(base + 24, A0, A1, A2, A3, mx0, mn0, mx1, mn1);
    const int rem = n & 7;
    if (rem) {
        const float4* br = base + (nfull << 3);
        #pragma unroll
        for (int j = 0; j < 7; ++j) {
            if (j < rem) {
                float4 t = br[j];
                float y = fmaf(t.x, A0, fmaf(t.y, A1, fmaf(t.z, A2, t.w * A3)));
                mx0 = fmaxf(mx0, y);
                mn0 = fminf(mn0, y);
            }
        }
    }
    dmax = fmaxf(mx0, mx1);
    dmin = fminf(mn0, mn1);
}

#define PAIRS 4

__global__ __launch_bounds__(256) void pfn_kernel(
    const float* __restrict__ features,   // (N, 32, 4)
    const int*   __restrict__ num_points, // (N,)
    const int*   __restrict__ coors,      // (N, 4)
    const float* __restrict__ W,          // (64, 10)
    const float* __restrict__ gamma,      // (64,)
    const float* __restrict__ beta,       // (64,)
    const float* __restrict__ rmean,      // (64,)
    const float* __restrict__ rvar,       // (64,)
    float*       __restrict__ out,        // (N, 64)
    int nTotal)
{
    __shared__ float4 lds[4 * PAIRS * 64];   // 4 waves x 4 pairs x 64 float4 = 16 KB

    const int lane = threadIdx.x & 63;
    const int wid  = threadIdx.x >> 6;
    const int wv   = blockIdx.x * 4 + wid;
    const int nPairs = (nTotal + 1) >> 1;
    const int pb = wv * PAIRS;
    if (pb >= nPairs) return;

    // ---- indices for 4 pairs (clamped duplicates benign on the tail wave) ----
    int p[PAIRS], iA[PAIRS], iB[PAIRS];
    bool hB[PAIRS];
    #pragma unroll
    for (int q = 0; q < PAIRS; ++q) {
        p[q]  = (pb + q < nPairs) ? (pb + q) : (nPairs - 1);
        iA[q] = 2 * p[q];
        hB[q] = (2 * p[q] + 1 < nTotal);
        iB[q] = hB[q] ? (2 * p[q] + 1) : (nTotal - 1);
    }

    // ---- load burst: 4x 1KB features + 8 num_points + 8 coors, all in flight ----
    const float4* fbase = reinterpret_cast<const float4*>(features);
    float4 f[PAIRS];
    #pragma unroll
    for (int q = 0; q < PAIRS; ++q) f[q] = fbase[(size_t)p[q] * 64 + lane];

    int nA[PAIRS], nB[PAIRS];
    int4 cA[PAIRS], cB[PAIRS];
    #pragma unroll
    for (int q = 0; q < PAIRS; ++q) {
        nA[q] = num_points[iA[q]];
        nB[q] = num_points[iB[q]];
        cA[q] = reinterpret_cast<const int4*>(coors)[iA[q]];
        cB[q] = reinterpret_cast<const int4*>(coors)[iB[q]];
    }

    // ---- channel constants (amortized over 4 pairs) ----
    const int o = lane;
    const float w0 = W[o*10+0], w1 = W[o*10+1], w2 = W[o*10+2], w3 = W[o*10+3],
                w4 = W[o*10+4], w5 = W[o*10+5], w6 = W[o*10+6], w7 = W[o*10+7],
                w8 = W[o*10+8], w9 = W[o*10+9];
    const float a = gamma[o] / sqrtf(rvar[o] + 1e-3f);
    const float b = fmaf(-rmean[o], a, beta[o]);
    const float A0 = a*(w0+w4+w7), A1 = a*(w1+w5+w8), A2 = a*(w2+w6+w9), A3 = a*w3;

    // ---- LDS stage (per-wave 4KB: pair q at +q*64; A pts 0..31, B pts 32..63) ----
    float4* slot = &lds[wid * (PAIRS * 64)];
    #pragma unroll
    for (int q = 0; q < PAIRS; ++q) slot[q * 64 + lane] = f[q];

    // ---- per-pair DPP sums -> means -> K -> C (C-deferral keeps this off scan path) ----
    float CA[PAIRS], CB[PAIRS];
    #pragma unroll
    for (int q = 0; q < PAIRS; ++q) {
        float sAx, sBx, sAy, sBy, sAz, sBz;
        half_sums(f[q].x, sAx, sBx);
        half_sums(f[q].y, sAy, sBy);
        half_sums(f[q].z, sAz, sBz);
        const float rcA = __builtin_amdgcn_rcpf((float)nA[q]);
        const float rcB = __builtin_amdgcn_rcpf((float)nB[q]);
        const float KA = -((sAx*rcA)*w4 + (sAy*rcA)*w5 + (sAz*rcA)*w6
                         + fmaf((float)cA[q].z, 0.2f, 0.1f)*w7
                         + fmaf((float)cA[q].y, 0.2f, -39.9f)*w8
                         + fmaf((float)cA[q].x, 4.0f, -1.0f)*w9);
        const float KB = -((sBx*rcB)*w4 + (sBy*rcB)*w5 + (sBz*rcB)*w6
                         + fmaf((float)cB[q].z, 0.2f, 0.1f)*w7
                         + fmaf((float)cB[q].y, 0.2f, -39.9f)*w8
                         + fmaf((float)cB[q].x, 4.0f, -1.0f)*w9);
        CA[q] = fmaf(a, KA, b);
        CB[q] = fmaf(a, KB, b);
    }

    // compiler-only fence: keep scan reads after the LDS writes (same-wave DS RAW is
    // in-order in HW; validated R6).
    asm volatile("" ::: "memory");

    // ---- exact-n scans + epilogue per pair (4 independent streams) ----
    #pragma unroll
    for (int q = 0; q < PAIRS; ++q) {
        float dAmax, dAmin, dBmax, dBmin;
        scan_pillar(slot + q * 64,      nA[q], A0, A1, A2, A3, dAmax, dAmin);
        scan_pillar(slot + q * 64 + 32, nB[q], A0, A1, A2, A3, dBmax, dBmin);

        float vmaxA = dAmax + CA[q], vminA = dAmin + CA[q];
        float vmaxB = dBmax + CB[q], vminB = dBmin + CB[q];
        if (nA[q] < 32) { vmaxA = fmaxf(vmaxA, b); vminA = fminf(vminA, b); }
        if (nB[q] < 32) { vmaxB = fmaxf(vmaxB, b); vminB = fminf(vminB, b); }

        const f32x2 gA = gelu2((f32x2){vmaxA, vminA});
        const f32x2 gB = gelu2((f32x2){vmaxB, vminB});

        out[(size_t)iA[q] * 64 + o] = fmaxf(gA.x, gA.y);
        if (hB[q]) out[(size_t)iB[q] * 64 + o] = fmaxf(gB.x, gB.y);
    }
}

extern "C" void kernel_launch(void* const* d_in, const int* in_sizes, int n_in,
                              void* d_out, int out_size, void* d_ws, size_t ws_size,
                              hipStream_t stream) {
    const float* features   = (const float*)d_in[0];
    const int*   num_points = (const int*)  d_in[1];
    const int*   coors      = (const int*)  d_in[2];
    const float* W          = (const float*)d_in[3];
    const float* gamma      = (const float*)d_in[4];
    const float* beta       = (const float*)d_in[5];
    const float* rmean      = (const float*)d_in[6];
    const float* rvar       = (const float*)d_in[7];
    float* out = (float*)d_out;

    const int nTotal = in_sizes[1];  // N pillars

    // 4 waves x 4 pairs per wave = 16 pairs/block; N=100k -> 3125 blocks, 12500 waves, no tail
    const int nPairs = (nTotal + 1) / 2;
    int blocks = (nPairs + 15) / 16;
    if (blocks < 1) blocks = 1;
    pfn_kernel<<<blocks, 256, 0, stream>>>(features, num_points, coors, W,
                                           gamma, beta, rmean, rvar, out, nTotal);
}

// Round 14
// 122.554 us; speedup vs baseline: 1.1394x; 1.0383x over previous
//
#include <hip/hip_runtime.h>
#include <cmath>

// PillarFeatureNet fused: augment(10ch) -> linear(64) -> BN(inference) -> exact GELU -> max over points.
// Key algebra: y[m][o] = f0*A0 + f1*A1 + f2*A2 + f3*A3 + C_pillar  (C-deferred: scan dot only).
// GELU valley-shaped => max_m gelu(y_m) = max(gelu(max y), gelu(min y)): 2 gelus per (n,o).
// Masked points contribute y = b (BN of 0), merged once when num_points < 32.
// points_mean sums ALL 32 raw rows (reference semantics); mask applies only to the matmul.
//
// R14 == R6 verbatim (best verified: harness 121.64us, pfn ~39.6us). R12/R13 submissions of
// this same source hit container-acquire failures (no kernel diagnostic) -> resubmit.
// Structural ledger R2-R11: VALU-count cuts (R4/R9) null; DS-elimination via readlane (R10)
// regressed (+VALU > -DS); deeper per-wave batching (R8/R11) regressed (VGPR/occupancy).
// At this optimum the VALU pipe (~24-30us busy/CU) and DS pipe (~17-33us, 33 broadcast
// ds_read_b128/pair) are jointly near-saturated; remaining trades are ~1:1 cycle parity.
//   - C-DEFERRAL: scan tracks min/max of the dot part only; C added after.
//   - DPP reduction (row_shr 1/2/4/8 + row_bcast15 + readlane), pure VALU, no DS.
//   - dual-pair one-shot waves, 2-pairs-per-wave grid (6250 blocks): fine-grained HW
//     backfill beats persistent/deeper-batched alternatives under num_points variance.
//   - depth-1 preloaded dynamic scan; rcp means; packed branchless A&S gelu.

typedef float f32x2 __attribute__((ext_vector_type(2)));

__device__ __forceinline__ float max3f(float a, float b, float c) {
    float d;
    asm("v_max3_f32 %0, %1, %2, %3" : "=v"(d) : "v"(a), "v"(b), "v"(c));
    return d;
}
__device__ __forceinline__ float min3f(float a, float b, float c) {
    float d;
    asm("v_min3_f32 %0, %1, %2, %3" : "=v"(d) : "v"(a), "v"(b), "v"(c));
    return d;
}
__device__ __forceinline__ f32x2 pk_fma(f32x2 a, f32x2 b, f32x2 c) {
    f32x2 d;
    asm("v_pk_fma_f32 %0, %1, %2, %3" : "=v"(d) : "v"(a), "v"(b), "v"(c));
    return d;
}
__device__ __forceinline__ f32x2 pk_mul(f32x2 a, f32x2 b) {
    f32x2 d;
    asm("v_pk_mul_f32 %0, %1, %2" : "=v"(d) : "v"(a), "v"(b));
    return d;
}
__device__ __forceinline__ float fast_exp2(float a) {
    float d;
    asm("v_exp_f32 %0, %1" : "=v"(d) : "v"(a));
    return d;
}

// Packed exact-GELU for 2 values (A&S 7.1.26 erf, branchless). |err| ~2e-6 abs.
__device__ __forceinline__ f32x2 gelu2(f32x2 x) {
    const f32x2 c_t    = {0.70710678f, 0.70710678f};
    const f32x2 c_p    = {0.3275911f, 0.3275911f};
    const f32x2 c_one  = {1.0f, 1.0f};
    const f32x2 b1 = {-0.254829592f, -0.254829592f};
    const f32x2 b2 = { 0.284496736f,  0.284496736f};
    const f32x2 b3 = {-1.421413741f, -1.421413741f};
    const f32x2 b4 = { 1.453152027f,  1.453152027f};
    const f32x2 b5 = {-1.061405429f, -1.061405429f};
    const f32x2 c_k = {-1.02013963f, -1.02013963f};   // arg = -t^2*log2(e)

    f32x2 ax = {fabsf(x.x), fabsf(x.y)};
    f32x2 t  = pk_mul(ax, c_t);
    f32x2 u  = pk_fma(t, c_p, c_one);
    f32x2 s  = {__builtin_amdgcn_rcpf(u.x), __builtin_amdgcn_rcpf(u.y)};
    f32x2 poly = pk_fma(b5, s, b4);
    poly = pk_fma(poly, s, b3);
    poly = pk_fma(poly, s, b2);
    poly = pk_fma(poly, s, b1);
    poly = pk_mul(poly, s);
    f32x2 t3  = pk_mul(ax, c_k);
    f32x2 arg = pk_mul(t, t3);
    f32x2 e   = {fast_exp2(arg.x), fast_exp2(arg.y)};
    f32x2 E   = pk_fma(poly, e, c_one);
    f32x2 h   = pk_mul(x, (f32x2){0.5f, 0.5f});
    f32x2 hax = pk_mul(ax, (f32x2){0.5f, 0.5f});
    return pk_fma(hax, E, h);
}

// DPP half-wave sums: returns sum(lanes 0..31) and sum(lanes 32..63). Pure VALU (no DS pipe).
template <int CTRL, int ROW_MASK>
__device__ __forceinline__ float dpp_add(float v) {
    int x = __builtin_amdgcn_update_dpp(0, __builtin_bit_cast(int, v), CTRL, ROW_MASK, 0xf, false);
    return v + __builtin_bit_cast(float, x);
}
__device__ __forceinline__ void half_sums(float v, float& sA, float& sB) {
    v = dpp_add<0x111, 0xf>(v);   // row_shr:1
    v = dpp_add<0x112, 0xf>(v);   // row_shr:2
    v = dpp_add<0x114, 0xf>(v);   // row_shr:4
    v = dpp_add<0x118, 0xf>(v);   // row_shr:8  -> lane15/31/47/63 hold 16-lane sums
    v = dpp_add<0x142, 0xa>(v);   // row_bcast:15 into rows 1,3 -> lane31/63 hold 32-lane sums
    sA = __builtin_bit_cast(float, __builtin_amdgcn_readlane(__builtin_bit_cast(int, v), 31));
    sB = __builtin_bit_cast(float, __builtin_amdgcn_readlane(__builtin_bit_cast(int, v), 63));
}

// C-deferred scan: min/max of dot(f, A) over points [0,n); depth-1 preload (safe over-read
// into padded LDS). n is wave-uniform -> no divergence.
__device__ __forceinline__ void scan_minmax(const float4* base, int n,
                                            float A0, float A1, float A2, float A3,
                                            float& dmax, float& dmin) {
    float vmax = -INFINITY, vmin = INFINITY;
    float4 t0 = base[0], t1 = base[1];          // t1 garbage if n==1 (unused)
    int m = 0;
    for (; m + 2 <= n; m += 2) {
        float4 u0 = base[m + 2], u1 = base[m + 3];   // preload next (padded, safe)
        float y0 = fmaf(t0.x, A0, fmaf(t0.y, A1, fmaf(t0.z, A2, t0.w * A3)));
        float y1 = fmaf(t1.x, A0, fmaf(t1.y, A1, fmaf(t1.z, A2, t1.w * A3)));
        vmax = max3f(vmax, y0, y1);
        vmin = min3f(vmin, y0, y1);
        t0 = u0; t1 = u1;
    }
    if (m < n) {
        float y = fmaf(t0.x, A0, fmaf(t0.y, A1, fmaf(t0.z, A2, t0.w * A3)));
        vmax = fmaxf(vmax, y);
        vmin = fminf(vmin, y);
    }
    dmax = vmax; dmin = vmin;
}

__global__ __launch_bounds__(256) void pfn_kernel(
    const float* __restrict__ features,   // (N, 32, 4)
    const int*   __restrict__ num_points, // (N,)
    const int*   __restrict__ coors,      // (N, 4)
    const float* __restrict__ W,          // (64, 10)
    const float* __restrict__ gamma,      // (64,)
    const float* __restrict__ beta,       // (64,)
    const float* __restrict__ rmean,      // (64,)
    const float* __restrict__ rvar,       // (64,)
    float*       __restrict__ out,        // (N, 64)
    int nTotal)
{
    // 4 waves x 2 pairs x 64 float4 = 512 slots + preload pad
    __shared__ float4 lds[520];

    const int lane = threadIdx.x & 63;
    const int wid  = threadIdx.x >> 6;
    const int wv   = blockIdx.x * 4 + wid;
    const int nPairs = (nTotal + 1) >> 1;
    const int p0 = wv * 2;
    if (p0 >= nPairs) return;
    const int p1 = (p0 + 1 < nPairs) ? (p0 + 1) : p0;   // clamp: duplicate work, benign

    // ---- issue both 1KB feature loads up front (latency overlaps everything below) ----
    const float4* fbase = reinterpret_cast<const float4*>(features);
    const float4 f0 = fbase[(size_t)p0 * 64 + lane];
    const float4 f1 = fbase[(size_t)p1 * 64 + lane];

    const int i0A = 2 * p0;
    const bool h0B = (2 * p0 + 1 < nTotal);
    const int i0B = h0B ? (2 * p0 + 1) : (nTotal - 1);
    const int i1A = 2 * p1;
    const bool h1B = (2 * p1 + 1 < nTotal);
    const int i1B = h1B ? (2 * p1 + 1) : (nTotal - 1);

    const int n0A = num_points[i0A], n0B = num_points[i0B];
    const int n1A = num_points[i1A], n1B = num_points[i1B];
    const int4 c0A = reinterpret_cast<const int4*>(coors)[i0A];
    const int4 c0B = reinterpret_cast<const int4*>(coors)[i0B];
    const int4 c1A = reinterpret_cast<const int4*>(coors)[i1A];
    const int4 c1B = reinterpret_cast<const int4*>(coors)[i1B];

    // lane == output channel o
    const int o = lane;
    const float w0 = W[o*10+0], w1 = W[o*10+1], w2 = W[o*10+2], w3 = W[o*10+3],
                w4 = W[o*10+4], w5 = W[o*10+5], w6 = W[o*10+6], w7 = W[o*10+7],
                w8 = W[o*10+8], w9 = W[o*10+9];
    const float a = gamma[o] / sqrtf(rvar[o] + 1e-3f);
    const float b = fmaf(-rmean[o], a, beta[o]);
    const float A0 = a*(w0+w4+w7), A1 = a*(w1+w5+w8), A2 = a*(w2+w6+w9), A3 = a*w3;

    // ---- LDS stage (per-wave 2KB: pair0 at +0, pair1 at +64) ----
    float4* slot = &lds[wid * 128];
    slot[lane]      = f0;
    slot[64 + lane] = f1;

    // ---- DPP half-wave sums (off critical path thanks to C-deferral) ----
    float s0Ax, s0Bx, s0Ay, s0By, s0Az, s0Bz;
    float s1Ax, s1Bx, s1Ay, s1By, s1Az, s1Bz;
    half_sums(f0.x, s0Ax, s0Bx);
    half_sums(f0.y, s0Ay, s0By);
    half_sums(f0.z, s0Az, s0Bz);
    half_sums(f1.x, s1Ax, s1Bx);
    half_sums(f1.y, s1Ay, s1By);
    half_sums(f1.z, s1Az, s1Bz);

    // means via v_rcp (<=1ulp), voxel-center offsets, K, C  (x4 pillars)
    const float rc0A = __builtin_amdgcn_rcpf((float)n0A);
    const float rc0B = __builtin_amdgcn_rcpf((float)n0B);
    const float rc1A = __builtin_amdgcn_rcpf((float)n1A);
    const float rc1B = __builtin_amdgcn_rcpf((float)n1B);

    const float K0A = -((s0Ax*rc0A)*w4 + (s0Ay*rc0A)*w5 + (s0Az*rc0A)*w6
                      + fmaf((float)c0A.z, 0.2f, 0.1f)*w7
                      + fmaf((float)c0A.y, 0.2f, -39.9f)*w8
                      + fmaf((float)c0A.x, 4.0f, -1.0f)*w9);
    const float K0B = -((s0Bx*rc0B)*w4 + (s0By*rc0B)*w5 + (s0Bz*rc0B)*w6
                      + fmaf((float)c0B.z, 0.2f, 0.1f)*w7
                      + fmaf((float)c0B.y, 0.2f, -39.9f)*w8
                      + fmaf((float)c0B.x, 4.0f, -1.0f)*w9);
    const float K1A = -((s1Ax*rc1A)*w4 + (s1Ay*rc1A)*w5 + (s1Az*rc1A)*w6
                      + fmaf((float)c1A.z, 0.2f, 0.1f)*w7
                      + fmaf((float)c1A.y, 0.2f, -39.9f)*w8
                      + fmaf((float)c1A.x, 4.0f, -1.0f)*w9);
    const float K1B = -((s1Bx*rc1B)*w4 + (s1By*rc1B)*w5 + (s1Bz*rc1B)*w6
                      + fmaf((float)c1B.z, 0.2f, 0.1f)*w7
                      + fmaf((float)c1B.y, 0.2f, -39.9f)*w8
                      + fmaf((float)c1B.x, 4.0f, -1.0f)*w9);
    const float C0A = fmaf(a, K0A, b), C0B = fmaf(a, K0B, b);
    const float C1A = fmaf(a, K1A, b), C1B = fmaf(a, K1B, b);

    // compiler-only fence: keep scan reads after the LDS writes (HW DS pipe is in-order
    // per wave, so no lgkmcnt drain needed for the same-wave RAW).
    asm volatile("" ::: "memory");

    // ---- C-deferred scans (n is wave-uniform; depth-1 preloaded) ----
    float d0Amax, d0Amin, d0Bmax, d0Bmin, d1Amax, d1Amin, d1Bmax, d1Bmin;
    scan_minmax(slot,      n0A, A0, A1, A2, A3, d0Amax, d0Amin);
    scan_minmax(slot + 32, n0B, A0, A1, A2, A3, d0Bmax, d0Bmin);
    scan_minmax(slot + 64, n1A, A0, A1, A2, A3, d1Amax, d1Amin);
    scan_minmax(slot + 96, n1B, A0, A1, A2, A3, d1Bmax, d1Bmin);

    float vmax0A = d0Amax + C0A, vmin0A = d0Amin + C0A;
    float vmax0B = d0Bmax + C0B, vmin0B = d0Bmin + C0B;
    float vmax1A = d1Amax + C1A, vmin1A = d1Amin + C1A;
    float vmax1B = d1Bmax + C1B, vmin1B = d1Bmin + C1B;

    if (n0A < 32) { vmax0A = fmaxf(vmax0A, b); vmin0A = fminf(vmin0A, b); }
    if (n0B < 32) { vmax0B = fmaxf(vmax0B, b); vmin0B = fminf(vmin0B, b); }
    if (n1A < 32) { vmax1A = fmaxf(vmax1A, b); vmin1A = fminf(vmin1A, b); }
    if (n1B < 32) { vmax1B = fmaxf(vmax1B, b); vmin1B = fminf(vmin1B, b); }

    // valley property + packed branchless gelu (4 independent evals: good ILP)
    const f32x2 g0A = gelu2((f32x2){vmax0A, vmin0A});
    const f32x2 g0B = gelu2((f32x2){vmax0B, vmin0B});
    const f32x2 g1A = gelu2((f32x2){vmax1A, vmin1A});
    const f32x2 g1B = gelu2((f32x2){vmax1B, vmin1B});

    out[(size_t)i0A * 64 + o] = fmaxf(g0A.x, g0A.y);
    if (h0B) out[(size_t)i0B * 64 + o] = fmaxf(g0B.x, g0B.y);
    out[(size_t)i1A * 64 + o] = fmaxf(g1A.x, g1A.y);
    if (h1B) out[(size_t)i1B * 64 + o] = fmaxf(g1B.x, g1B.y);
}

extern "C" void kernel_launch(void* const* d_in, const int* in_sizes, int n_in,
                              void* d_out, int out_size, void* d_ws, size_t ws_size,
                              hipStream_t stream) {
    const float* features   = (const float*)d_in[0];
    const int*   num_points = (const int*)  d_in[1];
    const int*   coors      = (const int*)  d_in[2];
    const float* W          = (const float*)d_in[3];
    const float* gamma      = (const float*)d_in[4];
    const float* beta       = (const float*)d_in[5];
    const float* rmean      = (const float*)d_in[6];
    const float* rvar       = (const float*)d_in[7];
    float* out = (float*)d_out;

    const int nTotal = in_sizes[1];  // N pillars

    // 4 waves x 2 consecutive pairs per wave = 8 pairs/block (verified-best grid)
    const int nPairs = (nTotal + 1) / 2;
    int blocks = (nPairs + 7) / 8;
    if (blocks < 1) blocks = 1;
    pfn_kernel<<<blocks, 256, 0, stream>>>(features, num_points, coors, W,
                                           gamma, beta, rmean, rvar, out, nTotal);
}